// Round 6
// baseline (221.575 us; speedup 1.0000x reference)
//
#include <hip/hip_runtime.h>
#include <stdint.h>

// ============================================================================
// SpikingUnifiedCoreFlow: 4-layer LIF chain, T=32, exact fixed-point via i8.
//
// R12: persistent multi-layer kernel. R10/R11 post-mortem: R7/R10/R11 all
// land at 105-106 us despite 2x different LDS traffic and 2x different
// occupancy -> the K-loop pipes are NOT binding; per-kernel fixed costs
// (4 launch gaps, ramp/drain, cold per-layer prologue) are. This round
// keeps R10's k_fused inner loop BIT-FOR-BIT (tile, pacing, epilogue) but
// runs all 4 layers in one kernel with a device-scope grid barrier:
//   __syncthreads (drains stores) -> thread0 RELEASE fetch_add(agent) ->
//   spin ACQUIRE >= 512*(layer+1) -> __syncthreads.
// Co-residency: 512 blocks = 2/CU exactly (64KB LDS/block, VGPR<=128 via
// __launch_bounds__(512,4)). Next layer's H0 B-panel (static planes data)
// is prefetched BEFORE the sync so its latency hides under convergence;
// per-layer prologue then matches R10 exactly (c=0 P1: amr+H1 in flight).
// k_prep zeroes the barrier counter each iteration (ws is re-poisoned).
// Workspace: planes 16MB @0 | Am0 512KB @16777216 | Am1 @17301504
//          | bar 4B @17825792
// ============================================================================

typedef __attribute__((ext_vector_type(4)))  int   i32x4;
typedef __attribute__((ext_vector_type(16))) int   i32x16;
typedef __attribute__((ext_vector_type(4)))  float f32x4;

#define SCALE_F 4294967296.0f   // 2^32
#define NSL 4

__device__ __forceinline__ void gload16(const void* g, void* l) {
    __builtin_amdgcn_global_load_lds(
        (const __attribute__((address_space(1))) void*)g,
        (__attribute__((address_space(3))) void*)l, 16, 0, 0);
}

// 16 bits -> 16 i8 bytes (0/1): nibble spread, no carries (disjoint shifts)
__device__ __forceinline__ i32x4 expand16(unsigned int f) {
    i32x4 r;
    #pragma unroll
    for (int d = 0; d < 4; ++d)
        r[d] = (int)((((f >> (4 * d)) & 0xFu) * 0x00204081u) & 0x01010101u);
    return r;
}

// ----------------------------------------------------- prep (merged) --------
// blocks 0..4095: digit decomposition; blocks 4096..4607: encode+transpose
__global__ void k_prep(const float* __restrict__ x, const float* __restrict__ w,
                       uint32_t* __restrict__ Am, signed char* __restrict__ planes,
                       unsigned* __restrict__ bar) {
    if (blockIdx.x == 0 && threadIdx.x == 0) *bar = 0;   // re-arm grid barrier
    if (blockIdx.x < 4096) {
        // ---- digits: 1M threads, 4 weights each ----
        int tid = blockIdx.x * 256 + threadIdx.x;
        int l = tid >> 18;
        int rest4 = (tid & 0x3FFFF) << 2;
        f32x4 wv = *reinterpret_cast<const f32x4*>(w + ((size_t)l << 20) + rest4);
        long long q[4];
        #pragma unroll
        for (int i = 0; i < 4; ++i) q[i] = llrintf(wv[i] * SCALE_F);  // exact
        #pragma unroll
        for (int s = 0; s < NSL; ++s) {
            uint32_t pack = 0;
            #pragma unroll
            for (int i = 0; i < 4; ++i) {
                int d = (int)(signed char)((unsigned char)(q[i] & 255));
                q[i] = (q[i] - d) >> 8;
                pack |= ((uint32_t)(unsigned char)d) << (8 * i);
            }
            *reinterpret_cast<uint32_t*>(planes + (((size_t)(l * NSL + s)) << 20) + rest4) = pack;
        }
    } else {
        // ---- encode+transpose: 2048 waves ----
        const int wid  = ((blockIdx.x - 4096) * 256 + threadIdx.x) >> 6;
        const int lane = threadIdx.x & 63;
        const int b = wid >> 4, kc = wid & 15;
        float v = x[b * 1024 + kc * 64 + lane];
        int N = (int)rintf(v * 32.0f);                 // jnp.round = half-to-even
        uint32_t bits = 0;
        if (N >= 32) {
            bits = 0xFFFFFFFFu;
        } else if (N > 0) {
            float spacing = 32.0f / (float)N;
            #pragma unroll
            for (int t = 0; t < 32; ++t) {
                float fm = fmodf((float)t, spacing);   // exact in IEEE
                if (fm < 1.0f) bits |= (1u << t);
            }
        }
        uint32_t cap = 0;
        #pragma unroll
        for (int t = 0; t < 32; ++t) {
            unsigned long long bal = __ballot((bits >> t) & 1u);
            if (lane == t)      cap = (uint32_t)bal;          // lanes 0..31: lo
            if (lane == t + 32) cap = (uint32_t)(bal >> 32);  // lanes 32..63: hi
        }
        const int t = lane & 31, ww = lane >> 5;
        Am[(size_t)(b * 32 + t) * 32 + kc * 2 + ww] = cap;
    }
}

// ------------------------------------------------------- grid barrier -------
__device__ __forceinline__ void grid_sync(unsigned* bar, unsigned target) {
    __syncthreads();                       // all block stores issued + drained
    if (threadIdx.x == 0) {
        __hip_atomic_fetch_add(bar, 1u, __ATOMIC_RELEASE, __HIP_MEMORY_SCOPE_AGENT);
        while (__hip_atomic_load(bar, __ATOMIC_ACQUIRE, __HIP_MEMORY_SCOPE_AGENT) < target)
            __builtin_amdgcn_s_sleep(2);
    }
    __syncthreads();
}

// ----------------------------------------------------------------- fused ----
// LDS/buf (32KB): slice s @ s*8192 : [row 0..63][8 slots][16B]; physical slot
// q holds GLOBAL k-granule q ^ (row&7) (source-pre-swizzle, conflict-free).
__global__ __launch_bounds__(512, 4) void k_fused_all(
        const signed char* __restrict__ planes,
        const float* __restrict__ th,
        uint32_t* Am0, uint32_t* Am1,
        float* __restrict__ out,
        unsigned* __restrict__ bar) {
    __shared__ alignas(16) signed char lds[2][32768];

    const int tid  = threadIdx.x;
    const int lane = tid & 63;
    const int wave = tid >> 6;             // 0..7
    const int mw   = wave >> 1;            // 0..3 : 32-row batch tile
    const int nw   = wave & 1;             // 0..1 : 32-col half
    const int lr   = lane & 31;
    const int hi   = lane >> 5;

    // bijective XCD mapping: each XCD owns 2 n-panels (512KB B, L2-resident)
    const int xc = blockIdx.x & 7, q = blockIdx.x >> 3;
    const int nTile = xc * 2 + (q & 1);    // 0..15
    const int mTile = q >> 1;              // 0..31
    const int mBase = mTile * 128, nBase = nTile * 64;

    // B staging sources (layer 0): 4 units(16B)/thread/chunk, pre-swizzled;
    // advanced by 4MB per layer.
    const signed char* srcB[NSL];
    {
        const int r0 = tid >> 3, qs = tid & 7;
        const int sw0 = (qs ^ (r0 & 7)) * 16;
        #pragma unroll
        for (int s = 0; s < NSL; ++s)
            srcB[s] = planes + ((size_t)s << 20)
                    + (size_t)(nBase + r0) * 1024 + sw0;
    }

    // per-thread B read addresses (dynamic part); slice base added separately
    int baddr[4];
    {
        const int brow = nw * 32 + lr;
        #pragma unroll
        for (int ks = 0; ks < 4; ++ks)
            baddr[ks] = brow * 128 + (((ks * 2 + hi) ^ (brow & 7)) * 16);
    }

    auto H0 = [&](int buf, int c) {        // slices 0,1 : 2 units/thread
        const int ko = c * 128;
        gload16(srcB[0] + ko, &lds[buf][0]    + tid * 16);
        gload16(srcB[1] + ko, &lds[buf][8192] + tid * 16);
    };
    auto H1 = [&](int buf, int c) {        // slices 2,3 : 2 units/thread
        const int ko = c * 128;
        gload16(srcB[2] + ko, &lds[buf][16384] + tid * 16);
        gload16(srcB[3] + ko, &lds[buf][24576] + tid * 16);
    };

    uint32_t* AmIn  = Am0;
    uint32_t* AmOut = Am1;

    #pragma unroll 1
    for (int layer = 0; layer < 4; ++layer) {
        const uint32_t* aRow = AmIn + (size_t)(mBase + mw * 32 + lr) * 32;

        // prologue: layer 0 issues H0 here; layers 1-3 issued it pre-sync.
        if (layer == 0) H0(0, 0);
        i32x4 amr[2];                      // per-chunk A bits, ping-pong
        amr[0] = *reinterpret_cast<const i32x4*>(aRow);
        H1(0, 0);

        i32x16 acc[NSL];
        #pragma unroll
        for (int s = 0; s < NSL; ++s)
            #pragma unroll
            for (int r = 0; r < 16; ++r) acc[s][r] = 0;

        #pragma unroll
        for (int c = 0; c < 8; ++c) {
            const int buf = c & 1;
            const signed char* lb = &lds[buf][0];

            // ---- phase 1: need H0(c)+A(c); H1(c)^2 stays in flight ----
            asm volatile("s_waitcnt vmcnt(2)" ::: "memory");
            __builtin_amdgcn_s_barrier();
            asm volatile("" ::: "memory");

            if (c + 1 < 8) {               // issue ALL of chunk c+1 here:
                H0(buf ^ 1, c + 1);        // P2 becomes pure compute, and
                amr[(c + 1) & 1] = *reinterpret_cast<const i32x4*>(aRow + (c + 1) * 4);
                H1(buf ^ 1, c + 1);        // H1 gets a full phase of flight
            }

            i32x4 af[4];                   // A fragments, reused in phase 2
            __builtin_amdgcn_s_setprio(1);
            #pragma unroll
            for (int ks = 0; ks < 4; ++ks) {
                af[ks] = expand16((((unsigned)amr[c & 1][ks]) >> (16 * hi)) & 0xFFFFu);
                #pragma unroll
                for (int s = 0; s < 2; ++s) {
                    i32x4 bf = *reinterpret_cast<const i32x4*>(lb + s * 8192 + baddr[ks]);
                    acc[s] = __builtin_amdgcn_mfma_i32_32x32x32_i8(af[ks], bf, acc[s], 0, 0, 0);
                }
            }
            __builtin_amdgcn_s_setprio(0);

            // ---- phase 2: need H1(c); c+1's 5 loads stay in flight ----
            if (c + 1 < 8) asm volatile("s_waitcnt vmcnt(5)" ::: "memory");
            else           asm volatile("s_waitcnt vmcnt(0)" ::: "memory");
            __builtin_amdgcn_s_barrier();
            asm volatile("" ::: "memory");

            __builtin_amdgcn_s_setprio(1);
            #pragma unroll
            for (int ks = 0; ks < 4; ++ks) {
                #pragma unroll
                for (int s = 0; s < 2; ++s) {
                    i32x4 bf = *reinterpret_cast<const i32x4*>(lb + (2 + s) * 8192 + baddr[ks]);
                    acc[2 + s] = __builtin_amdgcn_mfma_i32_32x32x32_i8(af[ks], bf, acc[2 + s], 0, 0, 0);
                }
            }
            __builtin_amdgcn_s_setprio(0);
        }

        // prefetch next layer's H0 chunk 0 into buf 0 (planes are static;
        // buf 0's last reader finished before c=7 P1's barrier). Latency
        // hides under the epilogue + grid sync.
        if (layer < 3) {
            #pragma unroll
            for (int s = 0; s < NSL; ++s) srcB[s] += (size_t)NSL << 20;
            H0(0, 0);
        }

        // epilogue: combine slices -> int64, swap halves, LIF recurrence on
        // ALL lanes (hi halves compute identical bits), ballot-transpose.
        // C/D 32x32: col=lane&31, row(t) = (r&3) + 8*(r>>2) + 4*hi [m74/m101]
        const long long TH = llrintf(th[layer] * SCALE_F);
        const int batch = mTile * 4 + mw;
        uint32_t bits = 0;
        long long mmem = 0;
        #pragma unroll
        for (int half = 0; half < 2; ++half) {
            long long own[8], par[8];
            #pragma unroll
            for (int r = 0; r < 8; ++r) {
                long long v = 0;
                #pragma unroll
                for (int s = 0; s < NSL; ++s)
                    v += ((long long)acc[s][half * 8 + r]) << (8 * s);
                own[r] = v;
            }
            #pragma unroll
            for (int r = 0; r < 8; ++r) {
                int plo = __shfl((int)(uint32_t)own[r], lane ^ 32, 64);
                int phi = __shfl((int)(own[r] >> 32), lane ^ 32, 64);
                par[r] = ((long long)phi << 32) | (uint32_t)plo;
            }
            #pragma unroll
            for (int tq = 0; tq < 16; ++tq) {   // t = half*16 + tq
                const int idx = (tq >> 3) * 4 + (tq & 3);
                const int usePar = ((tq >> 2) & 1) ^ hi;
                long long v = usePar ? par[idx] : own[idx];
                mmem += v;
                if (mmem > TH) { mmem -= TH; bits |= (1u << (half * 16 + tq)); }
            }
        }

        if (layer < 3) {
            uint32_t cap = 0;
            #pragma unroll
            for (int t = 0; t < 32; ++t) {
                unsigned long long bal = __ballot((bits >> t) & 1u);
                if (lane == t) cap = (uint32_t)bal;   // lo32 = this nw half
            }
            if (hi == 0)
                AmOut[(size_t)(batch * 32 + lr) * 32 + nTile * 2 + nw] = cap;

            grid_sync(bar, 512u * (unsigned)(layer + 1));
            uint32_t* tmp = AmIn; AmIn = AmOut; AmOut = tmp;
        } else if (hi == 0) {
            out[batch * 1024 + nBase + nw * 32 + lr] = (float)__popc(bits) * 0.03125f;
        }
    }
}

// ---------------------------------------------------------------- launch ----
extern "C" void kernel_launch(void* const* d_in, const int* in_sizes, int n_in,
                              void* d_out, int out_size, void* d_ws, size_t ws_size,
                              hipStream_t stream) {
    const float* x  = (const float*)d_in[0];
    const float* w  = (const float*)d_in[1];
    const float* th = (const float*)d_in[2];
    float* out = (float*)d_out;
    char* ws = (char*)d_ws;

    signed char* planes = (signed char*)(ws);                 // 16 MB
    uint32_t*    Am0    = (uint32_t*)(ws + 16777216);         // 512 KB
    uint32_t*    Am1    = (uint32_t*)(ws + 17301504);         // 512 KB
    unsigned*    bar    = (unsigned*)(ws + 17825792);         // 4 B

    k_prep<<<4608, 256, 0, stream>>>(x, w, Am0, planes, bar);
    k_fused_all<<<512, 512, 0, stream>>>(planes, th, Am0, Am1, out, bar);
}

// Round 7
// 107.946 us; speedup vs baseline: 2.0526x; 2.0526x over previous
//
#include <hip/hip_runtime.h>
#include <stdint.h>

// ============================================================================
// SpikingUnifiedCoreFlow: 4-layer LIF chain, T=32, exact fixed-point via i8.
//
// R13: R10 structure (5 launches, proven 2-phase pacing) + K-MAJOR plane
// layout. R12's counters finally exposed k_fused: SQ_LDS_BANK_CONFLICT =
// exactly 4 cyc per ds_read_b128 -- the old q^(row&7) swizzle put each
// 8-lane group on 8 DIFFERENT 128B lines (diagonal), vs m134's conflict-
// free lane-linear pattern (8-lane group = one contiguous line). Fix by
// re-laying planes as [granule 0..63][row 0..1023][16B] per (layer,slice):
//  - staging: wave w copies granule c*8+w, 64 rows = contiguous 1KB/wave
//    (perfectly coalesced, source-pre-swizzle GONE);
//  - LDS slice = [kslot][row][16B]; fragment read addr = (ks*2+hi)*1024 +
//    brow*16 = lane-linear 16B stride = conflict-free (reads 16->12 cyc).
// Transpose scatter moved to k_prep writes (16B @ 16KB stride, L2-absorbed;
// prep reads stay coalesced 64B/lane). R12 also showed the grid-barrier
// persistent kernel costs ~38us/sync -> multi-launch restored.
// Pacing unchanged from R10: P1 vmcnt(2) { H0(c+1),A(c+1),H1(c+1) issued },
// P2 vmcnt(5), tail 0. af[4] expanded once per chunk, reused in P2.
// Workspace: planes 16MB @0 | Amask0 512KB @16777216 | Amask1 @17301504
// ============================================================================

typedef __attribute__((ext_vector_type(4)))  int   i32x4;
typedef __attribute__((ext_vector_type(16))) int   i32x16;
typedef __attribute__((ext_vector_type(4)))  float f32x4;

#define SCALE_F 4294967296.0f   // 2^32
#define NSL 4

__device__ __forceinline__ void gload16(const void* g, void* l) {
    __builtin_amdgcn_global_load_lds(
        (const __attribute__((address_space(1))) void*)g,
        (__attribute__((address_space(3))) void*)l, 16, 0, 0);
}

// 16 bits -> 16 i8 bytes (0/1): nibble spread, no carries (disjoint shifts)
__device__ __forceinline__ i32x4 expand16(unsigned int f) {
    i32x4 r;
    #pragma unroll
    for (int d = 0; d < 4; ++d)
        r[d] = (int)((((f >> (4 * d)) & 0xFu) * 0x00204081u) & 0x01010101u);
    return r;
}

// ----------------------------------------------------- prep (merged) --------
// blocks 0..1023: digit decomposition into K-major planes; each thread owns
// one (layer,row,granule) = 16 consecutive weights. blocks 1024..1535:
// encode+transpose (unchanged).
__global__ void k_prep(const float* __restrict__ x, const float* __restrict__ w,
                       uint32_t* __restrict__ Am, signed char* __restrict__ planes) {
    if (blockIdx.x < 1024) {
        // ---- digits: 256K threads, 16 weights (one granule) each ----
        int tid = blockIdx.x * 256 + threadIdx.x;  // 0..262143
        int l    = tid >> 16;                      // layer 0..3
        int rest = tid & 0xFFFF;
        int row  = rest >> 6;                      // 0..1023 (neuron row)
        int g    = rest & 63;                      // k-granule 0..63
        const float* wp = w + ((size_t)l << 20) + (size_t)row * 1024 + g * 16;
        long long q[16];
        #pragma unroll
        for (int i = 0; i < 16; i += 4) {
            f32x4 wv = *reinterpret_cast<const f32x4*>(wp + i);
            q[i + 0] = llrintf(wv[0] * SCALE_F);   // exact scale (2^32)
            q[i + 1] = llrintf(wv[1] * SCALE_F);
            q[i + 2] = llrintf(wv[2] * SCALE_F);
            q[i + 3] = llrintf(wv[3] * SCALE_F);
        }
        #pragma unroll
        for (int s = 0; s < NSL; ++s) {
            i32x4 pk;
            #pragma unroll
            for (int e = 0; e < 4; ++e) {
                uint32_t pack = 0;
                #pragma unroll
                for (int i = 0; i < 4; ++i) {
                    int idx = e * 4 + i;
                    int d = (int)(signed char)((unsigned char)(q[idx] & 255));
                    q[idx] = (q[idx] - d) >> 8;
                    pack |= ((uint32_t)(unsigned char)d) << (8 * i);
                }
                pk[e] = (int)pack;
            }
            // K-major: byte = granule*16384 + row*16  (within 1MB slice)
            *reinterpret_cast<i32x4*>(planes + (((size_t)(l * NSL + s)) << 20)
                                      + (size_t)g * 16384 + row * 16) = pk;
        }
    } else {
        // ---- encode+transpose: 2048 waves ----
        const int wid  = ((blockIdx.x - 1024) * 256 + threadIdx.x) >> 6;
        const int lane = threadIdx.x & 63;
        const int b = wid >> 4, kc = wid & 15;
        float v = x[b * 1024 + kc * 64 + lane];
        int N = (int)rintf(v * 32.0f);                 // jnp.round = half-to-even
        uint32_t bits = 0;
        if (N >= 32) {
            bits = 0xFFFFFFFFu;
        } else if (N > 0) {
            float spacing = 32.0f / (float)N;
            #pragma unroll
            for (int t = 0; t < 32; ++t) {
                float fm = fmodf((float)t, spacing);   // exact in IEEE
                if (fm < 1.0f) bits |= (1u << t);
            }
        }
        uint32_t cap = 0;
        #pragma unroll
        for (int t = 0; t < 32; ++t) {
            unsigned long long bal = __ballot((bits >> t) & 1u);
            if (lane == t)      cap = (uint32_t)bal;          // lanes 0..31: lo
            if (lane == t + 32) cap = (uint32_t)(bal >> 32);  // lanes 32..63: hi
        }
        const int t = lane & 31, ww = lane >> 5;
        Am[(size_t)(b * 32 + t) * 32 + kc * 2 + ww] = cap;
    }
}

// ----------------------------------------------------------------- fused ----
// LDS/buf (32KB): slice s @ s*8192 : [kslot 0..7][row 0..63][16B] (K-major,
// linear -- no swizzle needed; reads are lane-linear = conflict-free).
__global__ __launch_bounds__(512, 4) void k_fused(
        const uint32_t* __restrict__ Am,
        const signed char* __restrict__ planes,
        const float* __restrict__ th,
        uint32_t* __restrict__ AmNext,     // null on last layer
        float* __restrict__ out,           // null except last layer
        int layer) {
    __shared__ alignas(16) signed char lds[2][32768];

    const int tid  = threadIdx.x;
    const int lane = tid & 63;
    const int wave = tid >> 6;             // 0..7
    const int mw   = wave >> 1;            // 0..3 : 32-row batch tile
    const int nw   = wave & 1;             // 0..1 : 32-col half
    const int lr   = lane & 31;
    const int hi   = lane >> 5;

    // bijective XCD mapping: each XCD owns 2 n-panels (512KB B, L2-resident)
    const int xc = blockIdx.x & 7, q = blockIdx.x >> 3;
    const int nTile = xc * 2 + (q & 1);    // 0..15
    const int mTile = q >> 1;              // 0..31
    const int mBase = mTile * 128, nBase = nTile * 64;

    // B staging sources (K-major): wave w stages kslot w, rows nBase+lane.
    // Per wave per slice per chunk: contiguous 1KB global read.
    const signed char* srcB[NSL];
    {
        const int ks0 = tid >> 6;          // kslot = wave id
        const int rr  = tid & 63;
        #pragma unroll
        for (int s = 0; s < NSL; ++s)
            srcB[s] = planes + (((size_t)(layer * NSL + s)) << 20)
                    + (size_t)ks0 * 16384 + (size_t)(nBase + rr) * 16;
    }
    // A bitmask row pointer (u32 words; row stride 32 words = 128B)
    const uint32_t* aRow = Am + (size_t)(mBase + mw * 32 + lr) * 32;

    // per-thread B read addresses: lane-linear 16B stride (conflict-free)
    int baddr[4];
    {
        const int brow = nw * 32 + lr;
        #pragma unroll
        for (int ks = 0; ks < 4; ++ks)
            baddr[ks] = (ks * 2 + hi) * 1024 + brow * 16;
    }

    i32x16 acc[NSL];
    #pragma unroll
    for (int s = 0; s < NSL; ++s)
        #pragma unroll
        for (int r = 0; r < 16; ++r) acc[s][r] = 0;

    auto H0 = [&](int buf, int c) {        // slices 0,1 : 2 units/thread
        const int ko = c * 131072;         // chunk = 8 granules = 128KB global
        gload16(srcB[0] + ko, &lds[buf][0]    + tid * 16);
        gload16(srcB[1] + ko, &lds[buf][8192] + tid * 16);
    };
    auto H1 = [&](int buf, int c) {        // slices 2,3 : 2 units/thread
        const int ko = c * 131072;
        gload16(srcB[2] + ko, &lds[buf][16384] + tid * 16);
        gload16(srcB[3] + ko, &lds[buf][24576] + tid * 16);
    };

    i32x4 amr[2];                          // per-chunk A bits, ping-pong
    H0(0, 0);
    amr[0] = *reinterpret_cast<const i32x4*>(aRow);
    H1(0, 0);

    #pragma unroll
    for (int c = 0; c < 8; ++c) {
        const int buf = c & 1;
        const signed char* lb = &lds[buf][0];

        // ---- phase 1: need H0(c)+A(c); H1(c)^2 stays in flight ----
        asm volatile("s_waitcnt vmcnt(2)" ::: "memory");
        __builtin_amdgcn_s_barrier();
        asm volatile("" ::: "memory");

        if (c + 1 < 8) {                   // issue ALL of chunk c+1 here:
            H0(buf ^ 1, c + 1);            // P2 becomes pure compute, and
            amr[(c + 1) & 1] = *reinterpret_cast<const i32x4*>(aRow + (c + 1) * 4);
            H1(buf ^ 1, c + 1);            // H1 gets a full phase of flight
        }

        i32x4 af[4];                       // A fragments, reused in phase 2
        __builtin_amdgcn_s_setprio(1);
        #pragma unroll
        for (int ks = 0; ks < 4; ++ks) {
            af[ks] = expand16((((unsigned)amr[c & 1][ks]) >> (16 * hi)) & 0xFFFFu);
            #pragma unroll
            for (int s = 0; s < 2; ++s) {
                i32x4 bf = *reinterpret_cast<const i32x4*>(lb + s * 8192 + baddr[ks]);
                acc[s] = __builtin_amdgcn_mfma_i32_32x32x32_i8(af[ks], bf, acc[s], 0, 0, 0);
            }
        }
        __builtin_amdgcn_s_setprio(0);

        // ---- phase 2: need H1(c); c+1's 5 loads stay in flight ----
        if (c + 1 < 8) asm volatile("s_waitcnt vmcnt(5)" ::: "memory");
        else           asm volatile("s_waitcnt vmcnt(0)" ::: "memory");
        __builtin_amdgcn_s_barrier();
        asm volatile("" ::: "memory");

        __builtin_amdgcn_s_setprio(1);
        #pragma unroll
        for (int ks = 0; ks < 4; ++ks) {
            #pragma unroll
            for (int s = 0; s < 2; ++s) {
                i32x4 bf = *reinterpret_cast<const i32x4*>(lb + (2 + s) * 8192 + baddr[ks]);
                acc[2 + s] = __builtin_amdgcn_mfma_i32_32x32x32_i8(af[ks], bf, acc[2 + s], 0, 0, 0);
            }
        }
        __builtin_amdgcn_s_setprio(0);
    }

    // epilogue: combine slices -> int64, swap halves, LIF recurrence on ALL
    // lanes (hi halves compute identical bits), ballot-transpose to next mask.
    // C/D 32x32: col=lane&31, row(t) = (r&3) + 8*(r>>2) + 4*hi  [m74/m101]
    const long long TH = llrintf(th[layer] * SCALE_F);
    const int batch = mTile * 4 + mw;
    uint32_t bits = 0;
    long long mmem = 0;
    #pragma unroll
    for (int half = 0; half < 2; ++half) {
        long long own[8], par[8];
        #pragma unroll
        for (int r = 0; r < 8; ++r) {
            long long v = 0;
            #pragma unroll
            for (int s = 0; s < NSL; ++s)
                v += ((long long)acc[s][half * 8 + r]) << (8 * s);
            own[r] = v;
        }
        #pragma unroll
        for (int r = 0; r < 8; ++r) {
            int plo = __shfl((int)(uint32_t)own[r], lane ^ 32, 64);
            int phi = __shfl((int)(own[r] >> 32), lane ^ 32, 64);
            par[r] = ((long long)phi << 32) | (uint32_t)plo;
        }
        #pragma unroll
        for (int tq = 0; tq < 16; ++tq) {   // t = half*16 + tq
            const int idx = (tq >> 3) * 4 + (tq & 3);
            const int usePar = ((tq >> 2) & 1) ^ hi;
            long long v = usePar ? par[idx] : own[idx];
            mmem += v;
            if (mmem > TH) { mmem -= TH; bits |= (1u << (half * 16 + tq)); }
        }
    }

    if (AmNext) {
        uint32_t cap = 0;
        #pragma unroll
        for (int t = 0; t < 32; ++t) {
            unsigned long long bal = __ballot((bits >> t) & 1u);
            if (lane == t) cap = (uint32_t)bal;   // lo32 = cols of this nw half
        }
        if (hi == 0)
            AmNext[(size_t)(batch * 32 + lr) * 32 + nTile * 2 + nw] = cap;
    } else if (hi == 0) {
        out[batch * 1024 + nBase + nw * 32 + lr] = (float)__popc(bits) * 0.03125f;
    }
}

// ---------------------------------------------------------------- launch ----
extern "C" void kernel_launch(void* const* d_in, const int* in_sizes, int n_in,
                              void* d_out, int out_size, void* d_ws, size_t ws_size,
                              hipStream_t stream) {
    const float* x  = (const float*)d_in[0];
    const float* w  = (const float*)d_in[1];
    const float* th = (const float*)d_in[2];
    float* out = (float*)d_out;
    char* ws = (char*)d_ws;

    signed char* planes = (signed char*)(ws);                 // 16 MB
    uint32_t*    Am0    = (uint32_t*)(ws + 16777216);         // 512 KB
    uint32_t*    Am1    = (uint32_t*)(ws + 17301504);         // 512 KB

    k_prep<<<1536, 256, 0, stream>>>(x, w, Am0, planes);

    uint32_t* Ain = Am0;
    uint32_t* Anx = Am1;
    for (int l = 0; l < 4; ++l) {
        k_fused<<<512, 512, 0, stream>>>(Ain, planes, th,
                                         (l < 3) ? Anx : nullptr,
                                         (l == 3) ? out : nullptr, l);
        uint32_t* tmp = Ain; Ain = Anx; Anx = tmp;
    }
}

// Round 9
// 103.251 us; speedup vs baseline: 2.1460x; 1.0455x over previous
//
#include <hip/hip_runtime.h>
#include <stdint.h>

// ============================================================================
// SpikingUnifiedCoreFlow: 4-layer LIF chain, T=32, exact fixed-point via i8.
//
// R14b: R14 with the const-qualifier compile fix (k_fused's planes is now
// non-const: it WRITES layer l+1's digit planes in the co-scheduled tail).
// R10 k_fused verbatim (proven best: 105.0) + digit co-scheduling:
//  (1) k_prep shrinks to encode + LAYER-0 digits only (~3us);
//  (2) each k_fused(l<3) block computes layer-(l+1)'s digit planes for its
//      2048-weight share AFTER the epilogue (acc dead -> no VGPR pressure,
//      no LDS use). Rides the block-retirement drain bubble; visibility via
//      kernel boundary. 512 blocks x 512 thr x 4 w = 1M weights = exact.
// k_fused inner loop, LDS layout (q^(row&7) swizzle), pacing (P1 vmcnt(2),
// P2 vmcnt(5), tail 0), epilogue: all bit-identical to R10.
// Workspace: planes 16MB @0 | Amask0 512KB @16777216 | Amask1 @17301504
// ============================================================================

typedef __attribute__((ext_vector_type(4)))  int   i32x4;
typedef __attribute__((ext_vector_type(16))) int   i32x16;
typedef __attribute__((ext_vector_type(4)))  float f32x4;

#define SCALE_F 4294967296.0f   // 2^32
#define NSL 4

__device__ __forceinline__ void gload16(const void* g, void* l) {
    __builtin_amdgcn_global_load_lds(
        (const __attribute__((address_space(1))) void*)g,
        (__attribute__((address_space(3))) void*)l, 16, 0, 0);
}

// 16 bits -> 16 i8 bytes (0/1): nibble spread, no carries (disjoint shifts)
__device__ __forceinline__ i32x4 expand16(unsigned int f) {
    i32x4 r;
    #pragma unroll
    for (int d = 0; d < 4; ++d)
        r[d] = (int)((((f >> (4 * d)) & 0xFu) * 0x00204081u) & 0x01010101u);
    return r;
}

// digit decomposition of 4 consecutive weights -> 4 planes (R10 packing)
__device__ __forceinline__ void digits4(const float* __restrict__ w,
                                        signed char* __restrict__ planes,
                                        int layer, int rest4) {
    f32x4 wv = *reinterpret_cast<const f32x4*>(w + ((size_t)layer << 20) + rest4);
    long long q[4];
    #pragma unroll
    for (int i = 0; i < 4; ++i) q[i] = llrintf(wv[i] * SCALE_F);  // exact
    #pragma unroll
    for (int s = 0; s < NSL; ++s) {
        uint32_t pack = 0;
        #pragma unroll
        for (int i = 0; i < 4; ++i) {
            int d = (int)(signed char)((unsigned char)(q[i] & 255));
            q[i] = (q[i] - d) >> 8;
            pack |= ((uint32_t)(unsigned char)d) << (8 * i);
        }
        *reinterpret_cast<uint32_t*>(planes + (((size_t)(layer * NSL + s)) << 20) + rest4) = pack;
    }
}

// ------------------------------------------------------------ prep ----------
// blocks 0..1023: layer-0 digit decomposition; blocks 1024..1535: encode.
__global__ void k_prep(const float* __restrict__ x, const float* __restrict__ w,
                       uint32_t* __restrict__ Am, signed char* __restrict__ planes) {
    if (blockIdx.x < 1024) {
        // ---- digits, layer 0 only: 256K threads, 4 weights each ----
        int tid = blockIdx.x * 256 + threadIdx.x;      // 0..262143
        digits4(w, planes, 0, tid << 2);
    } else {
        // ---- encode+transpose: 2048 waves ----
        const int wid  = ((blockIdx.x - 1024) * 256 + threadIdx.x) >> 6;
        const int lane = threadIdx.x & 63;
        const int b = wid >> 4, kc = wid & 15;
        float v = x[b * 1024 + kc * 64 + lane];
        int N = (int)rintf(v * 32.0f);                 // jnp.round = half-to-even
        uint32_t bits = 0;
        if (N >= 32) {
            bits = 0xFFFFFFFFu;
        } else if (N > 0) {
            float spacing = 32.0f / (float)N;
            #pragma unroll
            for (int t = 0; t < 32; ++t) {
                float fm = fmodf((float)t, spacing);   // exact in IEEE
                if (fm < 1.0f) bits |= (1u << t);
            }
        }
        uint32_t cap = 0;
        #pragma unroll
        for (int t = 0; t < 32; ++t) {
            unsigned long long bal = __ballot((bits >> t) & 1u);
            if (lane == t)      cap = (uint32_t)bal;          // lanes 0..31: lo
            if (lane == t + 32) cap = (uint32_t)(bal >> 32);  // lanes 32..63: hi
        }
        const int t = lane & 31, ww = lane >> 5;
        Am[(size_t)(b * 32 + t) * 32 + kc * 2 + ww] = cap;
    }
}

// ----------------------------------------------------------------- fused ----
// LDS/buf (32KB): slice s @ s*8192 : [row 0..63][8 slots][16B]; physical slot
// q holds GLOBAL k-granule q ^ (row&7) (source-pre-swizzle).
__global__ __launch_bounds__(512, 4) void k_fused(
        const uint32_t* __restrict__ Am,
        signed char* __restrict__ planes,  // non-const: writes dlayer's planes
        const float* __restrict__ th,
        const float* __restrict__ w,
        uint32_t* __restrict__ AmNext,     // null on last layer
        float* __restrict__ out,           // null except last layer
        int layer, int dlayer) {           // dlayer = layer+1 digits to build
    __shared__ alignas(16) signed char lds[2][32768];

    const int tid  = threadIdx.x;
    const int lane = tid & 63;
    const int wave = tid >> 6;             // 0..7
    const int mw   = wave >> 1;            // 0..3 : 32-row batch tile
    const int nw   = wave & 1;             // 0..1 : 32-col half
    const int lr   = lane & 31;
    const int hi   = lane >> 5;

    // bijective XCD mapping: each XCD owns 2 n-panels (512KB B, L2-resident)
    const int xc = blockIdx.x & 7, q = blockIdx.x >> 3;
    const int nTile = xc * 2 + (q & 1);    // 0..15
    const int mTile = q >> 1;              // 0..31
    const int mBase = mTile * 128, nBase = nTile * 64;

    // B staging sources: 4 units(16B)/thread/chunk, source-pre-swizzled
    const signed char* srcB[NSL];
    {
        const int r0 = tid >> 3, qs = tid & 7;
        const int sw0 = (qs ^ (r0 & 7)) * 16;
        #pragma unroll
        for (int s = 0; s < NSL; ++s)
            srcB[s] = planes + (((size_t)(layer * NSL + s)) << 20)
                    + (size_t)(nBase + r0) * 1024 + sw0;
    }
    // A bitmask row pointer (u32 words; row stride 32 words = 128B)
    const uint32_t* aRow = Am + (size_t)(mBase + mw * 32 + lr) * 32;

    // per-thread B read addresses (dynamic part); slice base added separately
    int baddr[4];
    {
        const int brow = nw * 32 + lr;
        #pragma unroll
        for (int ks = 0; ks < 4; ++ks)
            baddr[ks] = brow * 128 + (((ks * 2 + hi) ^ (brow & 7)) * 16);
    }

    i32x16 acc[NSL];
    #pragma unroll
    for (int s = 0; s < NSL; ++s)
        #pragma unroll
        for (int r = 0; r < 16; ++r) acc[s][r] = 0;

    auto H0 = [&](int buf, int c) {        // slices 0,1 : 2 units/thread
        const int ko = c * 128;
        gload16(srcB[0] + ko, &lds[buf][0]    + tid * 16);
        gload16(srcB[1] + ko, &lds[buf][8192] + tid * 16);
    };
    auto H1 = [&](int buf, int c) {        // slices 2,3 : 2 units/thread
        const int ko = c * 128;
        gload16(srcB[2] + ko, &lds[buf][16384] + tid * 16);
        gload16(srcB[3] + ko, &lds[buf][24576] + tid * 16);
    };

    i32x4 amr[2];                          // per-chunk A bits, ping-pong
    H0(0, 0);
    amr[0] = *reinterpret_cast<const i32x4*>(aRow);
    H1(0, 0);

    #pragma unroll
    for (int c = 0; c < 8; ++c) {
        const int buf = c & 1;
        const signed char* lb = &lds[buf][0];

        // ---- phase 1: need H0(c)+A(c); H1(c)^2 stays in flight ----
        asm volatile("s_waitcnt vmcnt(2)" ::: "memory");
        __builtin_amdgcn_s_barrier();
        asm volatile("" ::: "memory");

        if (c + 1 < 8) {                   // issue ALL of chunk c+1 here:
            H0(buf ^ 1, c + 1);            // P2 becomes pure compute, and
            amr[(c + 1) & 1] = *reinterpret_cast<const i32x4*>(aRow + (c + 1) * 4);
            H1(buf ^ 1, c + 1);            // H1 gets a full phase of flight
        }

        i32x4 af[4];                       // A fragments, reused in phase 2
        __builtin_amdgcn_s_setprio(1);
        #pragma unroll
        for (int ks = 0; ks < 4; ++ks) {
            af[ks] = expand16((((unsigned)amr[c & 1][ks]) >> (16 * hi)) & 0xFFFFu);
            #pragma unroll
            for (int s = 0; s < 2; ++s) {
                i32x4 bf = *reinterpret_cast<const i32x4*>(lb + s * 8192 + baddr[ks]);
                acc[s] = __builtin_amdgcn_mfma_i32_32x32x32_i8(af[ks], bf, acc[s], 0, 0, 0);
            }
        }
        __builtin_amdgcn_s_setprio(0);

        // ---- phase 2: need H1(c); c+1's 5 loads stay in flight ----
        if (c + 1 < 8) asm volatile("s_waitcnt vmcnt(5)" ::: "memory");
        else           asm volatile("s_waitcnt vmcnt(0)" ::: "memory");
        __builtin_amdgcn_s_barrier();
        asm volatile("" ::: "memory");

        __builtin_amdgcn_s_setprio(1);
        #pragma unroll
        for (int ks = 0; ks < 4; ++ks) {
            #pragma unroll
            for (int s = 0; s < 2; ++s) {
                i32x4 bf = *reinterpret_cast<const i32x4*>(lb + (2 + s) * 8192 + baddr[ks]);
                acc[2 + s] = __builtin_amdgcn_mfma_i32_32x32x32_i8(af[ks], bf, acc[2 + s], 0, 0, 0);
            }
        }
        __builtin_amdgcn_s_setprio(0);
    }

    // epilogue: combine slices -> int64, swap halves, LIF recurrence on ALL
    // lanes (hi halves compute identical bits), ballot-transpose to next mask.
    // C/D 32x32: col=lane&31, row(t) = (r&3) + 8*(r>>2) + 4*hi  [m74/m101]
    const long long TH = llrintf(th[layer] * SCALE_F);
    const int batch = mTile * 4 + mw;
    uint32_t bits = 0;
    long long mmem = 0;
    #pragma unroll
    for (int half = 0; half < 2; ++half) {
        long long own[8], par[8];
        #pragma unroll
        for (int r = 0; r < 8; ++r) {
            long long v = 0;
            #pragma unroll
            for (int s = 0; s < NSL; ++s)
                v += ((long long)acc[s][half * 8 + r]) << (8 * s);
            own[r] = v;
        }
        #pragma unroll
        for (int r = 0; r < 8; ++r) {
            int plo = __shfl((int)(uint32_t)own[r], lane ^ 32, 64);
            int phi = __shfl((int)(own[r] >> 32), lane ^ 32, 64);
            par[r] = ((long long)phi << 32) | (uint32_t)plo;
        }
        #pragma unroll
        for (int tq = 0; tq < 16; ++tq) {   // t = half*16 + tq
            const int idx = (tq >> 3) * 4 + (tq & 3);
            const int usePar = ((tq >> 2) & 1) ^ hi;
            long long v = usePar ? par[idx] : own[idx];
            mmem += v;
            if (mmem > TH) { mmem -= TH; bits |= (1u << (half * 16 + tq)); }
        }
    }

    if (AmNext) {
        uint32_t cap = 0;
        #pragma unroll
        for (int t = 0; t < 32; ++t) {
            unsigned long long bal = __ballot((bits >> t) & 1u);
            if (lane == t) cap = (uint32_t)bal;   // lo32 = cols of this nw half
        }
        if (hi == 0)
            AmNext[(size_t)(batch * 32 + lr) * 32 + nTile * 2 + nw] = cap;
    } else if (hi == 0) {
        out[batch * 1024 + nBase + nw * 32 + lr] = (float)__popc(bits) * 0.03125f;
    }

    // co-scheduled digit build for the NEXT layer (acc dead; rides the
    // block-retirement drain). 512 blocks x 512 thr x 4 weights = 1M = exact.
    if (dlayer < 4)
        digits4(w, planes, dlayer, (blockIdx.x * 512 + tid) << 2);
}

// ---------------------------------------------------------------- launch ----
extern "C" void kernel_launch(void* const* d_in, const int* in_sizes, int n_in,
                              void* d_out, int out_size, void* d_ws, size_t ws_size,
                              hipStream_t stream) {
    const float* x  = (const float*)d_in[0];
    const float* w  = (const float*)d_in[1];
    const float* th = (const float*)d_in[2];
    float* out = (float*)d_out;
    char* ws = (char*)d_ws;

    signed char* planes = (signed char*)(ws);                 // 16 MB
    uint32_t*    Am0    = (uint32_t*)(ws + 16777216);         // 512 KB
    uint32_t*    Am1    = (uint32_t*)(ws + 17301504);         // 512 KB

    k_prep<<<1536, 256, 0, stream>>>(x, w, Am0, planes);

    uint32_t* Ain = Am0;
    uint32_t* Anx = Am1;
    for (int l = 0; l < 4; ++l) {
        k_fused<<<512, 512, 0, stream>>>(Ain, planes, th, w,
                                         (l < 3) ? Anx : nullptr,
                                         (l == 3) ? out : nullptr,
                                         l, l + 1);
        uint32_t* tmp = Ain; Ain = Anx; Anx = tmp;
    }
}